// Round 9
// baseline (166.209 us; speedup 1.0000x reference)
//
#include <hip/hip_runtime.h>
#include <hip/hip_bf16.h>

#define BATCH 65536
#define IN    64
#define H     128
#define NA    16
#define H0PAD 132   // LDS row stride (bf16) for 128-col tiles: 2-way-free

typedef __bf16 bf16x8 __attribute__((ext_vector_type(8)));
typedef float  f32x4  __attribute__((ext_vector_type(4)));

union Frag { uint4 u; bf16x8 v; };

#define EXP2F(v) __builtin_amdgcn_exp2f(v)
#define RCPF(v)  __builtin_amdgcn_rcpf(v)
#define K1LOG 1.442695041f   // log2(e)
#define K2LOG 2.885390082f   // 2*log2(e)

// ALL tensors float32 (R5/R6: WRITE_SIZE == 65536*17*4B; f32 path passes).
__device__ __forceinline__ Frag g8f(const float* p) {
    const float4 a = *reinterpret_cast<const float4*>(p);
    const float4 b = *reinterpret_cast<const float4*>(p + 4);
    Frag f;
    f.v[0]=(__bf16)a.x; f.v[1]=(__bf16)a.y; f.v[2]=(__bf16)a.z; f.v[3]=(__bf16)a.w;
    f.v[4]=(__bf16)b.x; f.v[5]=(__bf16)b.y; f.v[6]=(__bf16)b.z; f.v[7]=(__bf16)b.w;
    return f;
}
__device__ __forceinline__ float clamp30(float v) {
    return __builtin_fminf(__builtin_fmaxf(v, -30.0f), 30.0f);
}
// h = sigmoid(o)*tanh(sigmoid(i)*tanh(g)); f-gate dead (c_prev=0). 4 exp+2 rcp;
// +-30 clamp keeps exp2 args < 128 (no inf) and is exact (sat long before 30).
__device__ __forceinline__ float lstm_h(float ip, float gp, float op) {
    ip = clamp30(ip); gp = clamp30(gp); op = clamp30(op);
    const float Ei = EXP2F(-K1LOG * ip);
    const float Eg = EXP2F( K2LOG * gp);
    const float c2 = (Eg - 1.0f) * RCPF((1.0f + Ei) * (Eg + 1.0f));
    const float Eo = EXP2F(-K1LOG * op);
    const float Ec = EXP2F( K2LOG * c2);
    return (Ec - 1.0f) * RCPF((1.0f + Eo) * (Ec + 1.0f));
}

// ================= K1: h0 = lstm0(x) -> d_ws (bf16 [BATCH][128]) ============
// c-split across blocks/waves: block b covers rows (b>>1)*64, c-half b&1;
// wave w owns c-tile ch = (b&1)*4 + w. Wih0 slice = 6 B-frags in REGISTERS.
// No LDS, no barriers, no loop-carried state: pure throughput kernel.
__global__ __launch_bounds__(256)
void k1_layer0(const float* __restrict__ x,
               const float* __restrict__ Wih0,
               const float* __restrict__ bih0,
               const float* __restrict__ bhh0,
               __hip_bfloat16* __restrict__ h0)
{
    const int wave = threadIdx.x >> 6, lane = threadIdx.x & 63;
    const int m16 = lane & 15, quad = lane >> 4;
    const int ch      = (blockIdx.x & 1) * 4 + wave;
    const int rowbase = (blockIdx.x >> 1) * 64;
    const int kGoff[3] = {0, 2 * H, 3 * H};   // gate rows: i, g, o
    const f32x4 vzero = {0.f, 0.f, 0.f, 0.f};

    Frag b0[3][2]; float bi[3];
#pragma unroll
    for (int G = 0; G < 3; ++G) {
        const int n = kGoff[G] + ch * 16 + m16;
#pragma unroll
        for (int kt = 0; kt < 2; ++kt)
            b0[G][kt] = g8f(Wih0 + (size_t)n * IN + kt * 32 + quad * 8);
        bi[G] = bih0[n] + bhh0[n];
    }

#pragma unroll
    for (int half = 0; half < 2; ++half) {    // 2 x 32 rows; caps live VGPRs
        Frag a[2][2];
#pragma unroll
        for (int si = 0; si < 2; ++si)
#pragma unroll
            for (int kt = 0; kt < 2; ++kt)
                a[si][kt] = g8f(x + (size_t)(rowbase + (half * 2 + si) * 16 + m16) * IN
                                + kt * 32 + quad * 8);

        f32x4 acc[3][2];
#pragma unroll
        for (int G = 0; G < 3; ++G)
#pragma unroll
            for (int si = 0; si < 2; ++si) acc[G][si] = vzero;

#pragma unroll
        for (int kt = 0; kt < 2; ++kt)
#pragma unroll
            for (int G = 0; G < 3; ++G)
#pragma unroll
                for (int si = 0; si < 2; ++si)
                    acc[G][si] = __builtin_amdgcn_mfma_f32_16x16x32_bf16(
                        a[si][kt].v, b0[G][kt].v, acc[G][si], 0, 0, 0);

#pragma unroll
        for (int si = 0; si < 2; ++si)
#pragma unroll
            for (int r = 0; r < 4; ++r) {
                const float h = lstm_h(acc[0][si][r] + bi[0],
                                       acc[1][si][r] + bi[1],
                                       acc[2][si][r] + bi[2]);
                const int row = rowbase + (half * 2 + si) * 16 + quad * 4 + r;
                h0[(size_t)row * H + ch * 16 + m16] = __float2bfloat16(h);
            }
    }
}

// ========== K2: h1 = lstm1(h0); policy/value heads -> out ===================
// Block = 512 threads = 8 waves = 8 c-tiles, owns 32 rows. Wih1 slice = 12
// B-frags in regs/wave. h0 tile staged once to LDS (read 1x per block).
__global__ __launch_bounds__(512)
void k2_layer1(const __hip_bfloat16* __restrict__ h0,
               const float* __restrict__ Wih1,
               const float* __restrict__ bih1,
               const float* __restrict__ bhh1,
               const float* __restrict__ Wp,
               const float* __restrict__ bp,
               const float* __restrict__ Wv,
               const float* __restrict__ bv,
               float* __restrict__ out)
{
    __shared__ __align__(16) __hip_bfloat16 h0s[32 * H0PAD];
    __shared__ __align__(16) __hip_bfloat16 hb1[32 * H0PAD];

    const int wave = threadIdx.x >> 6, lane = threadIdx.x & 63;
    const int m16 = lane & 15, quad = lane >> 4;
    const int rowbase = blockIdx.x * 32;
    const int kGoff[3] = {0, 2 * H, 3 * H};
    const f32x4 vzero = {0.f, 0.f, 0.f, 0.f};

    // stage h0 tile (32 x 128 bf16 = 8 KB): 512 threads x one uint4 each
    {
        const int t = threadIdx.x;
        const int rr = t >> 4, cc = (t & 15) * 8;
        *reinterpret_cast<uint4*>(h0s + rr * H0PAD + cc) =
            *reinterpret_cast<const uint4*>(h0 + (size_t)(rowbase + rr) * H + cc);
    }

    // Wih1 slice -> regs (12 frags = 48 VGPR); biases
    Frag b1[3][4]; float bi[3];
#pragma unroll
    for (int G = 0; G < 3; ++G) {
        const int n = kGoff[G] + wave * 16 + m16;
#pragma unroll
        for (int kt = 0; kt < 4; ++kt)
            b1[G][kt] = g8f(Wih1 + (size_t)n * H + kt * 32 + quad * 8);
        bi[G] = bih1[n] + bhh1[n];
    }
    __syncthreads();

    // GEMM2: gates1 = h0 @ Wih1[igo]^T  (A from LDS, B from regs)
    f32x4 acc[3][2];
#pragma unroll
    for (int G = 0; G < 3; ++G)
#pragma unroll
        for (int s = 0; s < 2; ++s) acc[G][s] = vzero;

#pragma unroll
    for (int kt = 0; kt < 4; ++kt) {
        Frag a[2];
#pragma unroll
        for (int s = 0; s < 2; ++s)
            a[s].u = *reinterpret_cast<const uint4*>(
                h0s + (s * 16 + m16) * H0PAD + kt * 32 + quad * 8);
#pragma unroll
        for (int G = 0; G < 3; ++G)
#pragma unroll
            for (int s = 0; s < 2; ++s)
                acc[G][s] = __builtin_amdgcn_mfma_f32_16x16x32_bf16(
                    a[s].v, b1[G][kt].v, acc[G][s], 0, 0, 0);
    }

#pragma unroll
    for (int s = 0; s < 2; ++s)
#pragma unroll
        for (int r = 0; r < 4; ++r) {
            const float h = lstm_h(acc[0][s][r] + bi[0],
                                   acc[1][s][r] + bi[1],
                                   acc[2][s][r] + bi[2]);
            hb1[(s * 16 + quad * 4 + r) * H0PAD + wave * 16 + m16] = __float2bfloat16(h);
        }
    __syncthreads();

    // Heads: waves 0,1 -> policy s-tile {0,1}; waves 2,3 -> value s-tile {0,1}
    if (wave < 4) {
        const int shead = wave & 1;
        Frag a3[4];
#pragma unroll
        for (int kt = 0; kt < 4; ++kt)
            a3[kt].u = *reinterpret_cast<const uint4*>(
                hb1 + (shead * 16 + m16) * H0PAD + kt * 32 + quad * 8);

        if (wave < 2) {
            Frag bh[4];
#pragma unroll
            for (int kt = 0; kt < 4; ++kt)
                bh[kt] = g8f(Wp + (size_t)m16 * H + kt * 32 + quad * 8);
            const float pb = bp[m16];
            f32x4 pa = vzero;
#pragma unroll
            for (int kt = 0; kt < 4; ++kt)
                pa = __builtin_amdgcn_mfma_f32_16x16x32_bf16(a3[kt].v, bh[kt].v, pa, 0, 0, 0);
#pragma unroll
            for (int r = 0; r < 4; ++r) {
                const int row = rowbase + shead * 16 + quad * 4 + r;
                out[(size_t)row * NA + m16] = pa[r] + pb;
            }
        } else {
            Frag bh[4];
#pragma unroll
            for (int kt = 0; kt < 4; ++kt) {
                if (m16 == 0) bh[kt] = g8f(Wv + kt * 32 + quad * 8);
                else          bh[kt].u = make_uint4(0u, 0u, 0u, 0u);
            }
            const float vb = bv[0];
            f32x4 va = vzero;
#pragma unroll
            for (int kt = 0; kt < 4; ++kt)
                va = __builtin_amdgcn_mfma_f32_16x16x32_bf16(a3[kt].v, bh[kt].v, va, 0, 0, 0);
            if (m16 == 0) {
#pragma unroll
                for (int r = 0; r < 4; ++r) {
                    const int row = rowbase + shead * 16 + quad * 4 + r;
                    out[(size_t)BATCH * NA + row] = va[r] + vb;
                }
            }
        }
    }
}

extern "C" void kernel_launch(void* const* d_in, const int* in_sizes, int n_in,
                              void* d_out, int out_size, void* d_ws, size_t ws_size,
                              hipStream_t stream) {
    // setup_inputs order: x, Wih0, Whh0, bih0, bhh0, Wih1, Whh1, bih1, bhh1, Wp, bp, Wv, bv
    // Whh0 (idx 2) / Whh1 (idx 6) dead (h_prev = 0); f-gate dead (c_prev = 0).
    // ALL tensors float32 (proven R5/R6). h0 handoff via d_ws (16.8 MB bf16);
    // d_ws re-poisoned each call but K1 fully rewrites it before K2 reads.
    __hip_bfloat16* h0ws = (__hip_bfloat16*)d_ws;

    k1_layer0<<<dim3(BATCH / 64 * 2), dim3(256), 0, stream>>>(
        (const float*)d_in[0], (const float*)d_in[1],
        (const float*)d_in[3], (const float*)d_in[4], h0ws);

    k2_layer1<<<dim3(BATCH / 32), dim3(512), 0, stream>>>(
        h0ws, (const float*)d_in[5], (const float*)d_in[7], (const float*)d_in[8],
        (const float*)d_in[9], (const float*)d_in[10],
        (const float*)d_in[11], (const float*)d_in[12], (float*)d_out);
}

// Round 10
// 135.664 us; speedup vs baseline: 1.2252x; 1.2252x over previous
//
#include <hip/hip_runtime.h>
#include <hip/hip_bf16.h>

#define BATCH 65536
#define IN    64
#define H     128
#define NA    16
#define H0PAD 132   // LDS row stride (bf16): 2-bank row shift, 2-way-free b128

typedef __bf16 bf16x8 __attribute__((ext_vector_type(8)));
typedef float  f32x4  __attribute__((ext_vector_type(4)));

union Frag { uint4 u; bf16x8 v; };

#define EXP2F(v) __builtin_amdgcn_exp2f(v)
#define RCPF(v)  __builtin_amdgcn_rcpf(v)
#define K1LOG 1.442695041f   // log2(e)
#define K2LOG 2.885390082f   // 2*log2(e)

// ALL tensors float32 (R5/R6: WRITE_SIZE == 65536*17*4B; f32 path passes).
__device__ __forceinline__ Frag g8f(const float* p) {
    const float4 a = *reinterpret_cast<const float4*>(p);
    const float4 b = *reinterpret_cast<const float4*>(p + 4);
    Frag f;
    f.v[0]=(__bf16)a.x; f.v[1]=(__bf16)a.y; f.v[2]=(__bf16)a.z; f.v[3]=(__bf16)a.w;
    f.v[4]=(__bf16)b.x; f.v[5]=(__bf16)b.y; f.v[6]=(__bf16)b.z; f.v[7]=(__bf16)b.w;
    return f;
}
__device__ __forceinline__ float clamp30(float v) {
    return __builtin_fminf(__builtin_fmaxf(v, -30.0f), 30.0f);
}
// h = sigmoid(o)*tanh(sigmoid(i)*tanh(g)); f-gate dead (c_prev=0). 4 exp+2 rcp;
// +-30 clamp keeps exp2 args < 128 (no inf) and is exact (sat long before 30).
__device__ __forceinline__ float lstm_h(float ip, float gp, float op) {
    ip = clamp30(ip); gp = clamp30(gp); op = clamp30(op);
    const float Ei = EXP2F(-K1LOG * ip);
    const float Eg = EXP2F( K2LOG * gp);
    const float c2 = (Eg - 1.0f) * RCPF((1.0f + Ei) * (Eg + 1.0f));
    const float Eo = EXP2F(-K1LOG * op);
    const float Ec = EXP2F( K2LOG * c2);
    return (Ec - 1.0f) * RCPF((1.0f + Eo) * (Ec + 1.0f));
}

// ================= K1: h0 = lstm0(x) -> d_ws (bf16 [BATCH][128]) ============
// R9 post-mortem: per-block setup (weight addr calc + cvt) dominated when each
// block did 32-64 rows. Now: weights load ONCE per wave, loop 4 row-tiles.
// No LDS, no barriers. block b: c-half = b&1 (wave -> c-tile), row-stripe b>>1.
__global__ __launch_bounds__(256)
void k1_layer0(const float* __restrict__ x,
               const float* __restrict__ Wih0,
               const float* __restrict__ bih0,
               const float* __restrict__ bhh0,
               __hip_bfloat16* __restrict__ h0)
{
    const int wave = threadIdx.x >> 6, lane = threadIdx.x & 63;
    const int m16 = lane & 15, quad = lane >> 4;
    const int ch     = (blockIdx.x & 1) * 4 + wave;
    const int stripe = blockIdx.x >> 1;           // 0..511
    const int kGoff[3] = {0, 2 * H, 3 * H};       // gate rows: i, g, o
    const f32x4 vzero = {0.f, 0.f, 0.f, 0.f};

    // ---- once per wave: Wih0 slice (6 frags = 24 VGPR) + biases ----
    Frag b0[3][2]; float bi[3];
#pragma unroll
    for (int G = 0; G < 3; ++G) {
        const int n = kGoff[G] + ch * 16 + m16;
#pragma unroll
        for (int kt = 0; kt < 2; ++kt)
            b0[G][kt] = g8f(Wih0 + (size_t)n * IN + kt * 32 + quad * 8);
        bi[G] = bih0[n] + bhh0[n];
    }

    for (int it = 0; it < 4; ++it) {
        const int rowbase = (stripe * 4 + it) * 32;

        Frag a[2][2];
#pragma unroll
        for (int s = 0; s < 2; ++s)
#pragma unroll
            for (int kt = 0; kt < 2; ++kt)
                a[s][kt] = g8f(x + (size_t)(rowbase + s * 16 + m16) * IN + kt * 32 + quad * 8);

        f32x4 acc[3][2];
#pragma unroll
        for (int G = 0; G < 3; ++G)
#pragma unroll
            for (int s = 0; s < 2; ++s) acc[G][s] = vzero;
#pragma unroll
        for (int kt = 0; kt < 2; ++kt)
#pragma unroll
            for (int G = 0; G < 3; ++G)
#pragma unroll
                for (int s = 0; s < 2; ++s)
                    acc[G][s] = __builtin_amdgcn_mfma_f32_16x16x32_bf16(
                        a[s][kt].v, b0[G][kt].v, acc[G][s], 0, 0, 0);

#pragma unroll
        for (int s = 0; s < 2; ++s)
#pragma unroll
            for (int r = 0; r < 4; ++r) {
                const float h = lstm_h(acc[0][s][r] + bi[0],
                                       acc[1][s][r] + bi[1],
                                       acc[2][s][r] + bi[2]);
                const int row = rowbase + s * 16 + quad * 4 + r;
                h0[(size_t)row * H + ch * 16 + m16] = __float2bfloat16(h);
            }
    }
}

// ========== K2: h1 = lstm1(h0); policy/value heads -> out ===================
// Block = 512 thr = 8 waves (wave = c-tile), loops 4 x 32-row tiles.
// Wih1 slice + head weights resident in regs; h0 double-buffered in LDS.
__global__ __launch_bounds__(512)
void k2_layer1(const __hip_bfloat16* __restrict__ h0,
               const float* __restrict__ Wih1,
               const float* __restrict__ bih1,
               const float* __restrict__ bhh1,
               const float* __restrict__ Wp,
               const float* __restrict__ bp,
               const float* __restrict__ Wv,
               const float* __restrict__ bv,
               float* __restrict__ out)
{
    __shared__ __align__(16) __hip_bfloat16 h0s[2][32 * H0PAD];  // 2 x 8.25 KB
    __shared__ __align__(16) __hip_bfloat16 hb1[32 * H0PAD];     // 8.25 KB

    const int wave = threadIdx.x >> 6, lane = threadIdx.x & 63;
    const int m16 = lane & 15, quad = lane >> 4;
    const int t = threadIdx.x;
    const int kGoff[3] = {0, 2 * H, 3 * H};
    const f32x4 vzero = {0.f, 0.f, 0.f, 0.f};

    // ---- once per wave: Wih1 slice (12 frags = 48 VGPR) + biases ----
    Frag b1[3][4]; float bi[3];
#pragma unroll
    for (int G = 0; G < 3; ++G) {
        const int n = kGoff[G] + wave * 16 + m16;
#pragma unroll
        for (int kt = 0; kt < 4; ++kt)
            b1[G][kt] = g8f(Wih1 + (size_t)n * H + kt * 32 + quad * 8);
        bi[G] = bih1[n] + bhh1[n];
    }
    // ---- head weights: waves 0,1 policy; waves 2,3 value ----
    Frag bh[4]; float hbias = 0.f;
    if (wave < 2) {
#pragma unroll
        for (int kt = 0; kt < 4; ++kt)
            bh[kt] = g8f(Wp + (size_t)m16 * H + kt * 32 + quad * 8);
        hbias = bp[m16];
    } else if (wave < 4) {
#pragma unroll
        for (int kt = 0; kt < 4; ++kt) {
            if (m16 == 0) bh[kt] = g8f(Wv + kt * 32 + quad * 8);
            else          bh[kt].u = make_uint4(0u, 0u, 0u, 0u);
        }
        hbias = bv[0];
    }

    // ---- stage tile 0 (32 x 128 bf16 = 8 KB = one uint4 per thread) ----
    const int srr = t >> 4, scc = (t & 15) * 8;
    *reinterpret_cast<uint4*>(&h0s[0][srr * H0PAD + scc]) =
        *reinterpret_cast<const uint4*>(h0 + (size_t)(blockIdx.x * 128 + srr) * H + scc);
    __syncthreads();

    for (int it = 0; it < 4; ++it) {
        const int buf = it & 1;
        const int rowbase = blockIdx.x * 128 + it * 32;

        // GEMM2: gates1 = h0 @ Wih1[igo]^T  (A from LDS, B regs)
        f32x4 acc[3][2];
#pragma unroll
        for (int G = 0; G < 3; ++G)
#pragma unroll
            for (int s = 0; s < 2; ++s) acc[G][s] = vzero;
#pragma unroll
        for (int kt = 0; kt < 4; ++kt) {
            Frag a[2];
#pragma unroll
            for (int s = 0; s < 2; ++s)
                a[s].u = *reinterpret_cast<const uint4*>(
                    &h0s[buf][(s * 16 + m16) * H0PAD + kt * 32 + quad * 8]);
#pragma unroll
            for (int G = 0; G < 3; ++G)
#pragma unroll
                for (int s = 0; s < 2; ++s)
                    acc[G][s] = __builtin_amdgcn_mfma_f32_16x16x32_bf16(
                        a[s].v, b1[G][kt].v, acc[G][s], 0, 0, 0);
        }

        // prefetch-stage next tile into the other buffer (overlaps epilogue)
        if (it + 1 < 4)
            *reinterpret_cast<uint4*>(&h0s[buf ^ 1][srr * H0PAD + scc]) =
                *reinterpret_cast<const uint4*>(
                    h0 + (size_t)(rowbase + 32 + srr) * H + scc);

        // epilogue -> hb1 (C-layout row = quad*4+r, col = wave*16+m16)
#pragma unroll
        for (int s = 0; s < 2; ++s)
#pragma unroll
            for (int r = 0; r < 4; ++r) {
                const float h = lstm_h(acc[0][s][r] + bi[0],
                                       acc[1][s][r] + bi[1],
                                       acc[2][s][r] + bi[2]);
                hb1[(s * 16 + quad * 4 + r) * H0PAD + wave * 16 + m16] =
                    __float2bfloat16(h);
            }
        __syncthreads();

        // heads on waves 0..3 (s-tile = wave&1)
        if (wave < 4) {
            const int shead = wave & 1;
            Frag a3[4];
#pragma unroll
            for (int kt = 0; kt < 4; ++kt)
                a3[kt].u = *reinterpret_cast<const uint4*>(
                    &hb1[(shead * 16 + m16) * H0PAD + kt * 32 + quad * 8]);
            f32x4 ha = vzero;
#pragma unroll
            for (int kt = 0; kt < 4; ++kt)
                ha = __builtin_amdgcn_mfma_f32_16x16x32_bf16(a3[kt].v, bh[kt].v, ha, 0, 0, 0);
            if (wave < 2) {
#pragma unroll
                for (int r = 0; r < 4; ++r) {
                    const int row = rowbase + shead * 16 + quad * 4 + r;
                    out[(size_t)row * NA + m16] = ha[r] + hbias;
                }
            } else if (m16 == 0) {
#pragma unroll
                for (int r = 0; r < 4; ++r) {
                    const int row = rowbase + shead * 16 + quad * 4 + r;
                    out[(size_t)BATCH * NA + row] = ha[r] + hbias;
                }
            }
        }
        __syncthreads();   // hb1 + h0s[buf^1] safe for next iteration
    }
}

extern "C" void kernel_launch(void* const* d_in, const int* in_sizes, int n_in,
                              void* d_out, int out_size, void* d_ws, size_t ws_size,
                              hipStream_t stream) {
    // setup_inputs order: x, Wih0, Whh0, bih0, bhh0, Wih1, Whh1, bih1, bhh1, Wp, bp, Wv, bv
    // Whh0 (idx 2) / Whh1 (idx 6) dead (h_prev = 0); f-gate dead (c_prev = 0).
    // ALL tensors float32 (proven R5/R6). h0 handoff via d_ws (16.8 MB bf16);
    // K1 fully rewrites it before K2 reads.
    __hip_bfloat16* h0ws = (__hip_bfloat16*)d_ws;

    k1_layer0<<<dim3(1024), dim3(256), 0, stream>>>(
        (const float*)d_in[0], (const float*)d_in[1],
        (const float*)d_in[3], (const float*)d_in[4], h0ws);

    k2_layer1<<<dim3(BATCH / 128), dim3(512), 0, stream>>>(
        h0ws, (const float*)d_in[5], (const float*)d_in[7], (const float*)d_in[8],
        (const float*)d_in[9], (const float*)d_in[10],
        (const float*)d_in[11], (const float*)d_in[12], (float*)d_out);
}

// Round 12
// 128.972 us; speedup vs baseline: 1.2887x; 1.0519x over previous
//
#include <hip/hip_runtime.h>
#include <hip/hip_bf16.h>

#define BATCH 65536
#define IN    64
#define H     128
#define NA    16
#define NBLK  512                        // 2 blocks/CU
#define RPB   32                         // rows per iteration
#define NITER (BATCH / (NBLK * RPB))     // 4
#define HPAD  136   // hb row stride (bf16): 272B, 16B-aligned, 2-way-free b128
#define W0PAD 72    // w0s row stride (bf16): 144B, 16B-aligned, 2-way-free

typedef __bf16 bf16x8 __attribute__((ext_vector_type(8)));
typedef float  f32x4  __attribute__((ext_vector_type(4)));

union Frag { uint4 u; bf16x8 v; };

#define EXP2F(v) __builtin_amdgcn_exp2f(v)
#define RCPF(v)  __builtin_amdgcn_rcpf(v)
#define K1LOG 1.442695041f   // log2(e)
#define K2LOG 2.885390082f   // 2*log2(e)

// ALL tensors float32 (R5/R6: WRITE_SIZE == 65536*17*4B; f32 path passes).
__device__ __forceinline__ Frag g8f(const float* p) {
    const float4 a = *reinterpret_cast<const float4*>(p);
    const float4 b = *reinterpret_cast<const float4*>(p + 4);
    Frag f;
    f.v[0]=(__bf16)a.x; f.v[1]=(__bf16)a.y; f.v[2]=(__bf16)a.z; f.v[3]=(__bf16)a.w;
    f.v[4]=(__bf16)b.x; f.v[5]=(__bf16)b.y; f.v[6]=(__bf16)b.z; f.v[7]=(__bf16)b.w;
    return f;
}
__device__ __forceinline__ float clamp30(float v) {
    return __builtin_fminf(__builtin_fmaxf(v, -30.0f), 30.0f);
}
// h = sigmoid(o)*tanh(sigmoid(i)*tanh(g)); f-gate dead (c_prev=0). 4 exp+2 rcp;
// +-30 clamp keeps exp2 args < 128 (no inf) and is exact (sat long before 30).
__device__ __forceinline__ float lstm_h(float ip, float gp, float op) {
    ip = clamp30(ip); gp = clamp30(gp); op = clamp30(op);
    const float Ei = EXP2F(-K1LOG * ip);
    const float Eg = EXP2F( K2LOG * gp);
    const float c2 = (Eg - 1.0f) * RCPF((1.0f + Ei) * (Eg + 1.0f));
    const float Eo = EXP2F(-K1LOG * op);
    const float Ec = EXP2F( K2LOG * c2);
    return (Ec - 1.0f) * RCPF((1.0f + Eo) * (Ec + 1.0f));
}

// Fused single kernel: 512 thr = 8 waves, wave = c-tile for both layers.
// Wih0 live gates (i,g,o) staged COMPACTLY -> 384 LDS rows (55.3 KB).
// Wih1 slice + head weights + biases resident in regs. 512 blocks x 4 iters
// of 32 rows; 2 blocks/CU = 16 waves/CU.
// R11 bug fixed: staging previously loaded raw rows 0..383 (i,f,g) leaving
// o-gate rows uninitialized; now remaps src_row = row<128 ? row : row+128
// so staged blocks {0,128,256} = gates {i,g,o}.
__global__ __launch_bounds__(512, 4)
void lstm_fused(const float* __restrict__ x,
                const float* __restrict__ Wih0,
                const float* __restrict__ bih0,
                const float* __restrict__ bhh0,
                const float* __restrict__ Wih1,
                const float* __restrict__ bih1,
                const float* __restrict__ bhh1,
                const float* __restrict__ Wp,
                const float* __restrict__ bp,
                const float* __restrict__ Wv,
                const float* __restrict__ bv,
                float* __restrict__ out)
{
    __shared__ __align__(16) __hip_bfloat16 w0s[384 * W0PAD];    // 55.3 KB
    __shared__ __align__(16) __hip_bfloat16 hb0[RPB * HPAD];     //  8.7 KB
    __shared__ __align__(16) __hip_bfloat16 hb1[RPB * HPAD];     //  8.7 KB

    const int wave = threadIdx.x >> 6, lane = threadIdx.x & 63;
    const int m16 = lane & 15, quad = lane >> 4;
    const int ch = wave;                         // c-tile 0..7
    const int kGoff[3] = {0, 2 * H, 3 * H};      // gate rows in Wih1: i, g, o
    const f32x4 vzero = {0.f, 0.f, 0.f, 0.f};

    // ---- stage live Wih0 gates (i,g,o) compactly -> 384 LDS rows, once ----
    for (int c = threadIdx.x; c < 384 * 8; c += 512) {
        const int row = c >> 3, colc = (c & 7) * 8;
        const int src_row = row < 128 ? row : row + 128;  // i@0, g@256, o@384
        Frag f = g8f(Wih0 + (size_t)src_row * IN + colc);
        *reinterpret_cast<uint4*>(w0s + row * W0PAD + colc) = f.u;
    }

    // ---- per-wave resident: Wih1 slice (12 frags) + biases ----
    Frag b1[3][4]; float bi0[3], bi1[3];
#pragma unroll
    for (int G = 0; G < 3; ++G) {
        const int n = kGoff[G] + ch * 16 + m16;
#pragma unroll
        for (int kt = 0; kt < 4; ++kt)
            b1[G][kt] = g8f(Wih1 + (size_t)n * H + kt * 32 + quad * 8);
        bi0[G] = bih0[n] + bhh0[n];
        bi1[G] = bih1[n] + bhh1[n];
    }
    // ---- head weights: waves 0,1 policy; waves 2,3 value ----
    Frag bh[4]; float hbias = 0.f;
    if (wave < 2) {
#pragma unroll
        for (int kt = 0; kt < 4; ++kt)
            bh[kt] = g8f(Wp + (size_t)m16 * H + kt * 32 + quad * 8);
        hbias = bp[m16];
    } else if (wave < 4) {
#pragma unroll
        for (int kt = 0; kt < 4; ++kt) {
            if (m16 == 0) bh[kt] = g8f(Wv + kt * 32 + quad * 8);
            else          bh[kt].u = make_uint4(0u, 0u, 0u, 0u);
        }
        hbias = bv[0];
    }
    __syncthreads();

    for (int it = 0; it < NITER; ++it) {
        const int rowbase = (blockIdx.x * NITER + it) * RPB;

        // ===== GEMM1: gates0 = x @ Wih0[igo]^T (A global, B LDS) =====
        Frag a[2][2];
#pragma unroll
        for (int s = 0; s < 2; ++s)
#pragma unroll
            for (int kt = 0; kt < 2; ++kt)
                a[s][kt] = g8f(x + (size_t)(rowbase + s * 16 + m16) * IN + kt * 32 + quad * 8);

        f32x4 acc[3][2];
#pragma unroll
        for (int G = 0; G < 3; ++G)
#pragma unroll
            for (int s = 0; s < 2; ++s) acc[G][s] = vzero;
#pragma unroll
        for (int kt = 0; kt < 2; ++kt) {
            Frag b[3];
#pragma unroll
            for (int G = 0; G < 3; ++G)
                b[G].u = *reinterpret_cast<const uint4*>(
                    w0s + (G * 128 + ch * 16 + m16) * W0PAD + kt * 32 + quad * 8);
#pragma unroll
            for (int G = 0; G < 3; ++G)
#pragma unroll
                for (int s = 0; s < 2; ++s)
                    acc[G][s] = __builtin_amdgcn_mfma_f32_16x16x32_bf16(
                        a[s][kt].v, b[G].v, acc[G][s], 0, 0, 0);
        }
#pragma unroll
        for (int s = 0; s < 2; ++s)
#pragma unroll
            for (int r = 0; r < 4; ++r) {
                const float h = lstm_h(acc[0][s][r] + bi0[0],
                                       acc[1][s][r] + bi0[1],
                                       acc[2][s][r] + bi0[2]);
                hb0[(s * 16 + quad * 4 + r) * HPAD + ch * 16 + m16] = __float2bfloat16(h);
            }
        __syncthreads();

        // ===== GEMM2: gates1 = h0 @ Wih1[igo]^T (A LDS, B regs) =====
        f32x4 acc2[3][2];
#pragma unroll
        for (int G = 0; G < 3; ++G)
#pragma unroll
            for (int s = 0; s < 2; ++s) acc2[G][s] = vzero;
#pragma unroll
        for (int kt = 0; kt < 4; ++kt) {
            Frag a2[2];
#pragma unroll
            for (int s = 0; s < 2; ++s)
                a2[s].u = *reinterpret_cast<const uint4*>(
                    hb0 + (s * 16 + m16) * HPAD + kt * 32 + quad * 8);
#pragma unroll
            for (int G = 0; G < 3; ++G)
#pragma unroll
                for (int s = 0; s < 2; ++s)
                    acc2[G][s] = __builtin_amdgcn_mfma_f32_16x16x32_bf16(
                        a2[s].v, b1[G][kt].v, acc2[G][s], 0, 0, 0);
        }
#pragma unroll
        for (int s = 0; s < 2; ++s)
#pragma unroll
            for (int r = 0; r < 4; ++r) {
                const float h = lstm_h(acc2[0][s][r] + bi1[0],
                                       acc2[1][s][r] + bi1[1],
                                       acc2[2][s][r] + bi1[2]);
                hb1[(s * 16 + quad * 4 + r) * HPAD + ch * 16 + m16] = __float2bfloat16(h);
            }
        __syncthreads();

        // ===== Heads (waves 0..3; s-tile = wave&1) =====
        // hb1 safe: next write is it+1's GEMM2 epilogue, which is after
        // barrier#1 of it+1 — and barrier#1 waits for heads to finish.
        if (wave < 4) {
            const int shead = wave & 1;
            Frag a3[4];
#pragma unroll
            for (int kt = 0; kt < 4; ++kt)
                a3[kt].u = *reinterpret_cast<const uint4*>(
                    hb1 + (shead * 16 + m16) * HPAD + kt * 32 + quad * 8);
            f32x4 ha = vzero;
#pragma unroll
            for (int kt = 0; kt < 4; ++kt)
                ha = __builtin_amdgcn_mfma_f32_16x16x32_bf16(a3[kt].v, bh[kt].v, ha, 0, 0, 0);
            if (wave < 2) {
#pragma unroll
                for (int r = 0; r < 4; ++r) {
                    const int row = rowbase + shead * 16 + quad * 4 + r;
                    out[(size_t)row * NA + m16] = ha[r] + hbias;
                }
            } else if (m16 == 0) {
#pragma unroll
                for (int r = 0; r < 4; ++r) {
                    const int row = rowbase + shead * 16 + quad * 4 + r;
                    out[(size_t)BATCH * NA + row] = ha[r] + hbias;
                }
            }
        }
    }
}

extern "C" void kernel_launch(void* const* d_in, const int* in_sizes, int n_in,
                              void* d_out, int out_size, void* d_ws, size_t ws_size,
                              hipStream_t stream) {
    // setup_inputs order: x, Wih0, Whh0, bih0, bhh0, Wih1, Whh1, bih1, bhh1, Wp, bp, Wv, bv
    // Whh0 (idx 2) / Whh1 (idx 6) dead (h_prev = 0); f-gate dead (c_prev = 0).
    // ALL tensors float32 (proven R5/R6).
    lstm_fused<<<dim3(NBLK), dim3(512), 0, stream>>>(
        (const float*)d_in[0], (const float*)d_in[1],
        (const float*)d_in[3], (const float*)d_in[4],
        (const float*)d_in[5], (const float*)d_in[7],
        (const float*)d_in[8], (const float*)d_in[9],
        (const float*)d_in[10], (const float*)d_in[11],
        (const float*)d_in[12], (float*)d_out);
}